// Round 19
// baseline (97.155 us; speedup 1.0000x reference)
//
#include <hip/hip_runtime.h>

constexpr int Fdim = 2000;
constexpr int Wdim = 4000;
constexpr int Edim = 16;
constexpr int Hdim = 64;
constexpr int Bdim = 256;
constexpr float kLog2e = 1.4426950408889634f;

constexpr int Mp = 2048;   // padded F
constexpr int Np = 4096;   // padded W
constexpr int NKS = 6;     // K=192: 3 tanh powers x 64 h, 32 per MFMA step

typedef _Float16 f16x8 __attribute__((ext_vector_type(8)));
typedef _Float16 f16x2 __attribute__((ext_vector_type(2)));
typedef float f32x4 __attribute__((ext_vector_type(4)));

__device__ __forceinline__ float fast_exp2(float x) {
#if __has_builtin(__builtin_amdgcn_exp2f)
  return __builtin_amdgcn_exp2f(x);
#else
  return exp2f(x);
#endif
}
__device__ __forceinline__ float fast_rcp(float x) {
#if __has_builtin(__builtin_amdgcn_rcpf)
  return __builtin_amdgcn_rcpf(x);
#else
  return 1.0f / x;
#endif
}
__device__ __forceinline__ float dev_tanh(float x) {
  return 1.0f - 2.0f * fast_rcp(fast_exp2(2.0f * kLog2e * x) + 1.0f);
}
__device__ __forceinline__ f16x2 pack_f16(float a, float b) {
  return __builtin_bit_cast(f16x2, __builtin_amdgcn_cvt_pkrtz(a, b));
}

// ---- DPP wave-64 sum (VALU pipe). Result valid in lane 63.
template <int CTRL>
__device__ __forceinline__ float dpp_part(float x) {
  return __int_as_float(
      __builtin_amdgcn_update_dpp(0, __float_as_int(x), CTRL, 0xF, 0xF, true));
}
__device__ __forceinline__ float wave64_sum(float x) {
  const float x0 = x;
  x += dpp_part<0x111>(x0);
  x += dpp_part<0x112>(x0);
  x += dpp_part<0x113>(x0);
  x += dpp_part<0x114>(x);
  x += dpp_part<0x118>(x);
  x += dpp_part<0x142>(x);
  x += dpp_part<0x143>(x);
  return x;
}

// fused: per block (32f x 128w): recompute A/B MFMA fragments in LDS
// (no global A2/B2 materialization), then GEMM1 -> exp2*mask -> GEMM2 ->
// atomic num/den. Mask read directly (guarded), issued early; its latency
// hides under the ~3K-cycle fragment build.
// LDS map (60KB + 16): A-frags 12KB | B-frags 48KB (sc 8KB + hembB 4KB
// overlay B after GEMM1) | s_any at +61440.
__global__ __launch_bounds__(256) void fused_kernel(
    const float* __restrict__ femb, const float* __restrict__ hemb,
    const float* __restrict__ Ww, const float* __restrict__ bwp,
    const float* __restrict__ Wu, const unsigned char* __restrict__ mask_b,
    float* __restrict__ num, float* __restrict__ den) {
  __shared__ __align__(16) char smem[61456];
  char* A_base = smem;
  char* B_base = smem + 12288;
  int* s_any = (int*)(smem + 61440);

  const int tid = threadIdx.x;
  const int wid = tid >> 6, lane = tid & 63;
  const int wr = wid >> 1, wc = wid & 1;

  // ---- bijective XCD swizzle (2048 blocks, 8 XCDs)
  const int lin = blockIdx.y * 32 + blockIdx.x;   // grid (32, 64)
  const int nl = (lin & 7) * 256 + (lin >> 3);
  const int bx = nl >> 6;   // w-block (128 w) [0,32)
  const int by = nl & 63;   // f-block (32 f)  [0,64)
  const int fblk = by * 32;
  const int wblk = bx * 128;

  const int fbase = fblk + wr * 16;
  const int wbase = wblk + wc * 64;
  const int lrow = lane & 15, g = lane >> 4;

  // ---- EARLY: hemb values for hembB fragment (held in regs until GEMM2)
  float hv[8];
  {
    const int widx_l = tid >> 6, lane_h = tid & 63;
    const int e = lane_h & 15;
    const int wbh = wblk + widx_l * 32 + (lane_h >> 4) * 8;
#pragma unroll
    for (int i = 0; i < 8; ++i) {
      const int w = wbh + i;
      hv[i] = (w < Wdim) ? hemb[(size_t)w * Edim + e] : 0.f;
    }
  }

  // ---- mask layout detect (8KB probe; L2-hot after first block per XCD)
  if (tid == 0) *s_any = 0;
  __syncthreads();
  {
    int acc = 0;
    for (int i = tid; i < 8192; i += 256)
      if ((i & 3) != 0) acc |= mask_b[i];
    if (acc) atomicOr(s_any, 1);
  }
  __syncthreads();
  const int mbyte = *s_any;  // 1 = byte layout, 0 = int32
  __syncthreads();           // s_any region about to be reused (A build)

  // ---- EARLY: mask loads for this lane's (f, 4x4 w) tile
  const int f_m = fbase + lrow;
  const bool fok = (f_m < Fdim);
  unsigned int mdm[4];
  uint4 mi4[4];
  if (mbyte) {
#pragma unroll
    for (int mw = 0; mw < 4; ++mw) {
      const int w0 = wbase + mw * 16 + g * 4;
      mdm[mw] = (fok && w0 < Wdim)
                    ? *(const unsigned int*)(mask_b + (size_t)f_m * Wdim + w0)
                    : 0u;
    }
  } else {
    const int* mask_i = (const int*)mask_b;
#pragma unroll
    for (int mw = 0; mw < 4; ++mw) {
      const int w0 = wbase + mw * 16 + g * 4;
      mi4[mw] = (fok && w0 < Wdim)
                    ? *(const uint4*)(mask_i + (size_t)f_m * Wdim + w0)
                    : make_uint4(0u, 0u, 0u, 0u);
    }
  }

  // ---- build A-frags: 256 items = (oct = tid>>5, f_local = tid&31)
  {
    const int f_local = tid & 31, oct = tid >> 5;
    const int f = fblk + f_local;
    const int h0 = oct * 8;
    float p8[8];
    if (f < Fdim) {
      float s8[8] = {0.f, 0.f, 0.f, 0.f, 0.f, 0.f, 0.f, 0.f};
      const float4* fr = (const float4*)(femb + (size_t)f * Edim);
      float4 fq[4] = {fr[0], fr[1], fr[2], fr[3]};
      const float* fe = (const float*)fq;
#pragma unroll
      for (int e = 0; e < Edim; ++e) {
        const float4* wr2 = (const float4*)(Ww + e * Hdim + h0);
        float4 wa = wr2[0], wb2 = wr2[1];
        s8[0] = fmaf(fe[e], wa.x, s8[0]); s8[1] = fmaf(fe[e], wa.y, s8[1]);
        s8[2] = fmaf(fe[e], wa.z, s8[2]); s8[3] = fmaf(fe[e], wa.w, s8[3]);
        s8[4] = fmaf(fe[e], wb2.x, s8[4]); s8[5] = fmaf(fe[e], wb2.y, s8[5]);
        s8[6] = fmaf(fe[e], wb2.z, s8[6]); s8[7] = fmaf(fe[e], wb2.w, s8[7]);
      }
#pragma unroll
      for (int i = 0; i < 8; ++i) p8[i] = dev_tanh(s8[i]);
    } else {
#pragma unroll
      for (int i = 0; i < 8; ++i) p8[i] = 0.f;
    }
    const int gq = (h0 & 31) >> 3;
    const int fl = gq * 16 + (f_local & 15);
    const int ftl = f_local >> 4;
#pragma unroll
    for (int j = 0; j < 3; ++j) {
      const int ks = j * 2 + (h0 >> 5);
      f16x8 o;
#pragma unroll
      for (int i = 0; i < 8; ++i) {
        float pj = (j == 0) ? ((f < Fdim) ? 1.f : 0.f)
                 : (j == 1) ? p8[i]
                            : p8[i] * p8[i];
        o[i] = (_Float16)pj;
      }
      *(f16x8*)(A_base + (((ftl * NKS + ks) * 64 + fl) << 4)) = o;
    }
  }

  // ---- build B-frags: 1024 items = (oct = v>>7, w_local = v&127)
#pragma unroll
  for (int iter = 0; iter < 4; ++iter) {
    const int v = iter * 256 + tid;
    const int w_local = v & 127, oct = v >> 7;
    const int w = wblk + w_local;
    const int h0 = oct * 8;
    float q8[8];
    if (w < Wdim) {
      float t8[8];
      {
        const float4* br = (const float4*)(bwp + h0);
        float4 b0 = br[0], b1 = br[1];
        t8[0] = b0.x; t8[1] = b0.y; t8[2] = b0.z; t8[3] = b0.w;
        t8[4] = b1.x; t8[5] = b1.y; t8[6] = b1.z; t8[7] = b1.w;
      }
      const float4* hr = (const float4*)(hemb + (size_t)w * Edim);
      float4 hq[4] = {hr[0], hr[1], hr[2], hr[3]};
      const float* he = (const float*)hq;
#pragma unroll
      for (int e = 0; e < Edim; ++e) {
        const float4* wr2 = (const float4*)(Ww + (Edim + e) * Hdim + h0);
        float4 wa = wr2[0], wb2 = wr2[1];
        t8[0] = fmaf(he[e], wa.x, t8[0]); t8[1] = fmaf(he[e], wa.y, t8[1]);
        t8[2] = fmaf(he[e], wa.z, t8[2]); t8[3] = fmaf(he[e], wa.w, t8[3]);
        t8[4] = fmaf(he[e], wb2.x, t8[4]); t8[5] = fmaf(he[e], wb2.y, t8[5]);
        t8[6] = fmaf(he[e], wb2.z, t8[6]); t8[7] = fmaf(he[e], wb2.w, t8[7]);
      }
#pragma unroll
      for (int i = 0; i < 8; ++i) q8[i] = dev_tanh(t8[i]);
    } else {
#pragma unroll
      for (int i = 0; i < 8; ++i) q8[i] = 0.f;
    }
    float wu8[8];
    {
      const float4* ur = (const float4*)(Wu + h0);
      float4 u0 = ur[0], u1 = ur[1];
      wu8[0] = u0.x; wu8[1] = u0.y; wu8[2] = u0.z; wu8[3] = u0.w;
      wu8[4] = u1.x; wu8[5] = u1.y; wu8[6] = u1.z; wu8[7] = u1.w;
    }
    const int gq = (h0 & 31) >> 3;
    const int fl = gq * 16 + (w_local & 15);
    const int wtl = w_local >> 4;
#pragma unroll
    for (int j = 0; j < 3; ++j) {
      const int ks = j * 2 + (h0 >> 5);
      f16x8 o;
#pragma unroll
      for (int i = 0; i < 8; ++i) {
        float q = q8[i];
        float val = (j == 0) ? q : (j == 1) ? ((w < Wdim) ? 1.f - q * q : 0.f)
                                           : -q;
        o[i] = (_Float16)(wu8[i] * val);
      }
      *(f16x8*)(B_base + (((wtl * NKS + ks) * 64 + fl) << 4)) = o;
    }
  }
  __syncthreads();

  // ---- GEMM1: accT[mw] = sc^T frags (col=f, row=w), mfma(B_w, A_f)
  f32x4 accT[4];
#pragma unroll
  for (int mw = 0; mw < 4; ++mw) accT[mw] = (f32x4){0.f, 0.f, 0.f, 0.f};
#pragma unroll 2
  for (int ks = 0; ks < NKS; ++ks) {
    f16x8 bw[4];
#pragma unroll
    for (int mw = 0; mw < 4; ++mw)
      bw[mw] = *(const f16x8*)(B_base +
                               ((((wc * 4 + mw) * NKS + ks) * 64 + lane) << 4));
    const f16x8 af =
        *(const f16x8*)(A_base + (((wr * NKS + ks) * 64 + lane) << 4));
#pragma unroll
    for (int mw = 0; mw < 4; ++mw)
      accT[mw] =
          __builtin_amdgcn_mfma_f32_16x16x32_f16(bw[mw], af, accT[mw], 0, 0, 0);
  }
  __syncthreads();  // B region about to be overlaid with sc + hembB

  // ---- epilogue: exp2 * mask -> fp16 -> swizzled sc tile (B overlay)
  char* sbase = B_base + wid * 2048;          // 4 waves x 2KB
  char* HB_base = B_base + 8192;              // 4KB hembB fragments
  const int sw = (lrow & 7) << 4;
  float denp = 0.f;
#pragma unroll
  for (int mw = 0; mw < 4; ++mw) {
    float mm[4];
    if (mbyte) {
#pragma unroll
      for (int r = 0; r < 4; ++r)
        mm[r] = (float)(((mdm[mw] >> (8 * r)) & 0xFFu) ? 1 : 0);
    } else {
      mm[0] = mi4[mw].x ? 1.f : 0.f;
      mm[1] = mi4[mw].y ? 1.f : 0.f;
      mm[2] = mi4[mw].z ? 1.f : 0.f;
      mm[3] = mi4[mw].w ? 1.f : 0.f;
    }
    float v[4];
#pragma unroll
    for (int r = 0; r < 4; ++r) {
      v[r] = fast_exp2(accT[mw][r] * kLog2e) * mm[r];
      denp += v[r];
    }
    const int wb0 = (mw * 16 + g * 4) * 2;
    *(f16x2*)(sbase + lrow * 128 + ((wb0 + 0) ^ sw)) = pack_f16(v[0], v[1]);
    *(f16x2*)(sbase + lrow * 128 + ((wb0 + 4) ^ sw)) = pack_f16(v[2], v[3]);
  }
  // hembB fragments from the early-loaded registers
  {
    f16x8 o;
#pragma unroll
    for (int i = 0; i < 8; ++i) o[i] = (_Float16)hv[i];
    *(f16x8*)(HB_base + (tid << 4)) = o;
  }
  __syncthreads();  // hembB visible to all waves (sc is wave-private)

  // ---- GEMM2: num[16f][16e] over this wave's 64 w
  f32x4 numT = (f32x4){0.f, 0.f, 0.f, 0.f};
#pragma unroll
  for (int kstep = 0; kstep < 2; ++kstep) {
    const f16x8 hb =
        *(const f16x8*)(HB_base + (((wc * 2 + kstep) * 64 + lane) << 4));
    const f16x8 scf =
        *(const f16x8*)(sbase + lrow * 128 + ((kstep * 64 + g * 16) ^ sw));
    numT = __builtin_amdgcn_mfma_f32_16x16x32_f16(scf, hb, numT, 0, 0, 0);
  }

  // ---- den: sum across the 4 lane-groups (same f, different g)
  denp += __shfl_xor(denp, 16, 64);
  denp += __shfl_xor(denp, 32, 64);

  // ---- accumulate global num/den with HW fp atomics
  if (lane < 16) unsafeAtomicAdd(&den[fbase + lrow], denp);
#pragma unroll
  for (int r = 0; r < 4; ++r) {
    const int f = fbase + g * 4 + r;
    unsafeAtomicAdd(&num[(size_t)f * Edim + lrow], numT[r]);
  }
}

// out[b][e] = sum_f values[b][f] * num[f][e] / den[f]
__global__ __launch_bounds__(256) void out_gemv_kernel(
    const float* __restrict__ values, const float* __restrict__ num,
    const float* __restrict__ den, float* __restrict__ out) {
  const int b = blockIdx.x, tid = threadIdx.x;
  float acc[Edim];
#pragma unroll
  for (int e = 0; e < Edim; ++e) acc[e] = 0.f;
  for (int f = tid; f < Fdim; f += 256) {
    float v = values[b * Fdim + f] * fast_rcp(den[f]);
    const float4* c4 = (const float4*)(num + (size_t)f * Edim);
    float4 c0 = c4[0], c1 = c4[1], c2 = c4[2], c3 = c4[3];
    float cr[Edim] = {c0.x, c0.y, c0.z, c0.w, c1.x, c1.y, c1.z, c1.w,
                      c2.x, c2.y, c2.z, c2.w, c3.x, c3.y, c3.z, c3.w};
#pragma unroll
    for (int e = 0; e < Edim; ++e) acc[e] = fmaf(v, cr[e], acc[e]);
  }
  __shared__ float s_red[4][Edim];
  const int lane = tid & 63, wv = tid >> 6;
#pragma unroll
  for (int e = 0; e < Edim; ++e) {
    float a = wave64_sum(acc[e]);
    if (lane == 63) s_red[wv][e] = a;
  }
  __syncthreads();
  if (tid < Edim)
    out[b * Edim + tid] =
        s_red[0][tid] + s_red[1][tid] + s_red[2][tid] + s_red[3][tid];
}

extern "C" void kernel_launch(void* const* d_in, const int* in_sizes, int n_in,
                              void* d_out, int out_size, void* d_ws,
                              size_t ws_size, hipStream_t stream) {
  const float* values = (const float*)d_in[0];
  const float* femb   = (const float*)d_in[1];
  const float* hemb   = (const float*)d_in[2];
  const float* Ww     = (const float*)d_in[3];
  const float* bw     = (const float*)d_in[4];
  const float* Wu     = (const float*)d_in[5];
  const unsigned char* mask = (const unsigned char*)d_in[6];
  float* out = (float*)d_out;
  float* ws = (float*)d_ws;

  // ws: num[Mp*Edim] | den[Mp]  (132 KB total)
  float* num = ws;
  float* den = ws + (size_t)Mp * Edim;

  hipMemsetAsync(num, 0, ((size_t)Mp * Edim + Mp) * sizeof(float), stream);

  fused_kernel<<<dim3(32, 64), dim3(256), 0, stream>>>(
      femb, hemb, Ww, bw, Wu, mask, num, den);

  out_gemv_kernel<<<dim3(Bdim), dim3(256), 0, stream>>>(values, num, den, out);
}

// Round 20
// 42.005 us; speedup vs baseline: 2.3129x; 2.3129x over previous
//
#include <hip/hip_runtime.h>

constexpr int Fdim = 2000;
constexpr int Wdim = 4000;
constexpr int Edim = 16;
constexpr int Hdim = 64;
constexpr int Bdim = 256;
constexpr float kLog2e = 1.4426950408889634f;

// ---- MFMA-path padded dims
constexpr int Mp = 2048;        // padded F
constexpr int Np = 4096;        // padded W
constexpr int NKS = 6;          // 192 / 32 k-steps (3 tanh powers x 64 h)
constexpr int NWRD = Np / 32;   // 128 mask words per row

typedef _Float16 f16x8 __attribute__((ext_vector_type(8)));
typedef _Float16 f16x2 __attribute__((ext_vector_type(2)));
typedef float f32x4 __attribute__((ext_vector_type(4)));

__device__ __forceinline__ float fast_exp2(float x) {
#if __has_builtin(__builtin_amdgcn_exp2f)
  return __builtin_amdgcn_exp2f(x);
#else
  return exp2f(x);
#endif
}
__device__ __forceinline__ float fast_rcp(float x) {
#if __has_builtin(__builtin_amdgcn_rcpf)
  return __builtin_amdgcn_rcpf(x);
#else
  return 1.0f / x;
#endif
}
__device__ __forceinline__ float dev_tanh(float x) {
  return 1.0f - 2.0f * fast_rcp(fast_exp2(2.0f * kLog2e * x) + 1.0f);
}
__device__ __forceinline__ f16x2 pack_f16(float a, float b) {
  return __builtin_bit_cast(f16x2, __builtin_amdgcn_cvt_pkrtz(a, b));
}

// ---- DPP wave-64 sum (VALU pipe). Result valid in lane 63.
template <int CTRL>
__device__ __forceinline__ float dpp_part(float x) {
  return __int_as_float(
      __builtin_amdgcn_update_dpp(0, __float_as_int(x), CTRL, 0xF, 0xF, true));
}
__device__ __forceinline__ float wave64_sum(float x) {
  const float x0 = x;
  x += dpp_part<0x111>(x0);
  x += dpp_part<0x112>(x0);
  x += dpp_part<0x113>(x0);
  x += dpp_part<0x114>(x);
  x += dpp_part<0x118>(x);
  x += dpp_part<0x142>(x);
  x += dpp_part<0x143>(x);
  return x;
}

// prep2 (R18, validated): one thread per output f16x8 for A2/B2.
// Series: tanh(s+t) ~= (p+q)(1-pq);  K = 3*64 = 192.
//   A2[(ftile*NKS+ks)*512 + lane*8 + i] = p(f, hb+i)^j
//   B2 likewise with Wu[h]*{q, 1-q^2, -q}; pads -> 0.
//   mbits[f][word] bit j <=> mask[f][word*32+j] != 0 (per-block layout
//     detection over the first 8KB of mask; L2-resident).
//   hembB: fragment-major hemb (fp16).
//   zero section: num[Mp*Edim] + den[Mp].
__global__ __launch_bounds__(256) void prep2_kernel(
    const float* __restrict__ femb, const float* __restrict__ hemb,
    const float* __restrict__ Ww, const float* __restrict__ bw,
    const float* __restrict__ Wu, const unsigned char* __restrict__ mask,
    _Float16* __restrict__ A2, _Float16* __restrict__ B2,
    unsigned int* __restrict__ mbits, _Float16* __restrict__ hembB,
    float* __restrict__ numden) {
  constexpr int PAV = 128 * NKS * 64;        // 49152  A2 vectors (192 blocks)
  constexpr int PBV = PAV + 256 * NKS * 64;  // 147456 B2 vectors (384)
  constexpr int PM = PBV + Mp * NWRD;        // 409600 mbits (1024)
  constexpr int PH = PM + (Np / 32) * 64;    // 417792 hembB (32)
  constexpr int PZ = PH + Mp * Edim + Mp;    // 452608 zero num+den (136)
  __shared__ int s_any;
  int idx = blockIdx.x * 256 + threadIdx.x;
  if (idx < PAV) {
    const int lane = idx & 63, rest = idx >> 6;
    const int ks = rest % NKS, ftile = rest / NKS;
    const int f = ftile * 16 + (lane & 15);
    const int k0 = ks * 32 + (lane >> 4) * 8;
    const int j = k0 >> 6, hb = k0 & 63;
    f16x8 o;
    if (f < Fdim) {
      float s8[8] = {0.f, 0.f, 0.f, 0.f, 0.f, 0.f, 0.f, 0.f};
#pragma unroll
      for (int e = 0; e < Edim; ++e) {
        const float fe = femb[f * Edim + e];
        const float* wr = Ww + e * Hdim + hb;
#pragma unroll
        for (int i = 0; i < 8; ++i) s8[i] = fmaf(fe, wr[i], s8[i]);
      }
#pragma unroll
      for (int i = 0; i < 8; ++i) {
        float p = dev_tanh(s8[i]);
        float pj = (j == 0) ? 1.f : (j == 1) ? p : p * p;
        o[i] = (_Float16)pj;
      }
    } else {
#pragma unroll
      for (int i = 0; i < 8; ++i) o[i] = (_Float16)0.f;
    }
    *(f16x8*)(A2 + (size_t)idx * 8) = o;
  } else if (idx < PBV) {
    const int v = idx - PAV;
    const int lane = v & 63, rest = v >> 6;
    const int ks = rest % NKS, wtile = rest / NKS;
    const int w = wtile * 16 + (lane & 15);
    const int k0 = ks * 32 + (lane >> 4) * 8;
    const int j = k0 >> 6, hb = k0 & 63;
    f16x8 o;
    if (w < Wdim) {
      float t8[8];
#pragma unroll
      for (int i = 0; i < 8; ++i) t8[i] = bw[hb + i];
#pragma unroll
      for (int e = 0; e < Edim; ++e) {
        const float he = hemb[(size_t)w * Edim + e];
        const float* wr = Ww + (Edim + e) * Hdim + hb;
#pragma unroll
        for (int i = 0; i < 8; ++i) t8[i] = fmaf(he, wr[i], t8[i]);
      }
#pragma unroll
      for (int i = 0; i < 8; ++i) {
        float q = dev_tanh(t8[i]);
        float val = (j == 0) ? q : (j == 1) ? (1.f - q * q) : -q;
        o[i] = (_Float16)(Wu[hb + i] * val);
      }
    } else {
#pragma unroll
      for (int i = 0; i < 8; ++i) o[i] = (_Float16)0.f;
    }
    *(f16x8*)(B2 + (size_t)v * 8) = o;
  } else if (idx < PM) {
    // ---- per-block mask-layout detection (8KB probe, L2-resident)
    if (threadIdx.x == 0) s_any = 0;
    __syncthreads();
    int acc = 0;
    for (int i = threadIdx.x; i < 8192; i += 256)
      if ((i & 3) != 0) acc |= mask[i];
    if (acc) atomicOr(&s_any, 1);
    __syncthreads();
    const int mbyte = s_any;  // 1 = byte layout, 0 = int32

    int t = idx - PBV;
    int f = t >> 7, word = t & 127;
    unsigned int bits = 0u;
    if (f < Fdim && word < Wdim / 32) {
      const int w0 = word * 32;
      if (mbyte) {  // byte layout: 32 bytes -> 2 uint4
        const uint4* p = (const uint4*)(mask + (size_t)f * Wdim + w0);
        uint4 u0 = p[0], u1 = p[1];
        unsigned int uu[8] = {u0.x, u0.y, u0.z, u0.w, u1.x, u1.y, u1.z, u1.w};
#pragma unroll
        for (int k = 0; k < 8; ++k)
#pragma unroll
          for (int b2 = 0; b2 < 4; ++b2)
            bits |= (((uu[k] >> (8 * b2)) & 0xFFu) ? 1u : 0u) << (k * 4 + b2);
      } else {       // int32 layout: 32 ints -> 8 uint4
        const uint4* p =
            (const uint4*)((const unsigned int*)mask + (size_t)f * Wdim + w0);
#pragma unroll
        for (int k = 0; k < 8; ++k) {
          uint4 u = p[k];
          bits |= (u.x ? 1u : 0u) << (4 * k + 0);
          bits |= (u.y ? 1u : 0u) << (4 * k + 1);
          bits |= (u.z ? 1u : 0u) << (4 * k + 2);
          bits |= (u.w ? 1u : 0u) << (4 * k + 3);
        }
      }
    }
    mbits[(size_t)f * NWRD + word] = bits;
  } else if (idx < PH) {
    int j = idx - PM;
    int lane = j & 63;
    int e = lane & 15;
    int wb = (j >> 6) * 32 + (lane >> 4) * 8;
    f16x8 v;
#pragma unroll
    for (int i = 0; i < 8; ++i) {
      int w = wb + i;
      v[i] = (w < Wdim) ? (_Float16)hemb[(size_t)w * Edim + e] : (_Float16)0.f;
    }
    *(f16x8*)(hembB + (size_t)j * 8) = v;
  } else if (idx < PZ) {
    numden[idx - PH] = 0.f;
  }
}

// score_ctx: fused, 32f x 64w per wave (accT[4][2], R12-validated subtile
// math), 1024 blocks, XCD-swizzled. ALL global loads contiguous (R15-18
// layout). First GEMM SWAPPED: mfma(B_w, A_f) -> D col=f, row=w. Epilogue:
// exp2*maskbit -> fp16 -> per-wave XOR-swizzled LDS tile [32f][64w].
// Second GEMM contracts w -> num[32f][16e]; HW fp32 atomics accumulate.
__global__ __launch_bounds__(256) void score_ctx_kernel(
    const _Float16* __restrict__ A2, const _Float16* __restrict__ B2,
    const unsigned int* __restrict__ mbits, const _Float16* __restrict__ hembB,
    float* __restrict__ num, float* __restrict__ den) {
  __shared__ __align__(16) char smem[16384];  // 4 KB per wave
  const int tid = threadIdx.x;
  const int wid = tid >> 6, lane = tid & 63;
  const int wr = wid >> 1, wc = wid & 1;

  // ---- bijective XCD swizzle (1024 blocks, 8 XCDs)
  const int lin = blockIdx.y * 32 + blockIdx.x;   // grid (32, 32)
  const int nl = (lin & 7) * 128 + (lin >> 3);
  const int bx = nl >> 5;   // w-tile (128 w) index [0,32)
  const int by = nl & 31;   // f-tile (64 f) index [0,32)

  const int fbase = by * 64 + wr * 32;   // wave owns 32 f
  const int wbase = bx * 128 + wc * 64;  // wave owns 64 w
  const int lrow = lane & 15, g = lane >> 4;

  // ---- EARLY issue: mask bits (2 x 8B) + hembB fragments
  uint2 mb[2];
#pragma unroll
  for (int nf = 0; nf < 2; ++nf)
    mb[nf] = *(const uint2*)(mbits + (size_t)(fbase + nf * 16 + lrow) * NWRD +
                             (wbase >> 5));
  const f16x8 hb0 =
      *(const f16x8*)(hembB + ((size_t)(wbase >> 5) + 0) * 512 + lane * 8);
  const f16x8 hb1 =
      *(const f16x8*)(hembB + ((size_t)(wbase >> 5) + 1) * 512 + lane * 8);

  // ---- first GEMM: accT[mw][nf] = sc^T frags (col=f, row=w)
  f32x4 accT[4][2];
#pragma unroll
  for (int mw = 0; mw < 4; ++mw)
#pragma unroll
    for (int nf = 0; nf < 2; ++nf) accT[mw][nf] = (f32x4){0.f, 0.f, 0.f, 0.f};

  const _Float16* Ab = A2 + ((size_t)(fbase >> 4) * NKS) * 512 + lane * 8;
  const _Float16* Bb = B2 + ((size_t)(wbase >> 4) * NKS) * 512 + lane * 8;
#pragma unroll 2
  for (int ks = 0; ks < NKS; ++ks) {
    f16x8 bw[4], af[2];
#pragma unroll
    for (int mw = 0; mw < 4; ++mw)
      bw[mw] = *(const f16x8*)(Bb + (size_t)(mw * NKS + ks) * 512);
#pragma unroll
    for (int nf = 0; nf < 2; ++nf)
      af[nf] = *(const f16x8*)(Ab + (size_t)(nf * NKS + ks) * 512);
#pragma unroll
    for (int mw = 0; mw < 4; ++mw)
#pragma unroll
      for (int nf = 0; nf < 2; ++nf)
        accT[mw][nf] = __builtin_amdgcn_mfma_f32_16x16x32_f16(
            bw[mw], af[nf], accT[mw][nf], 0, 0, 0);
  }

  // ---- epilogue: exp2 * maskbit -> fp16 -> swizzled LDS; den partials
  char* sbase = smem + wid * 4096;
  float denp[2] = {0.f, 0.f};
#pragma unroll
  for (int nf = 0; nf < 2; ++nf) {
    const int fl = nf * 16 + lrow;
    const int sw = (fl & 7) << 4;
#pragma unroll
    for (int mw = 0; mw < 4; ++mw) {
      float v[4];
#pragma unroll
      for (int r = 0; r < 4; ++r) {
        const int wl = mw * 16 + g * 4 + r;
        const unsigned int word = (wl < 32) ? mb[nf].x : mb[nf].y;
        const float m = (float)((word >> (wl & 31)) & 1u);
        v[r] = fast_exp2(accT[mw][nf][r] * kLog2e) * m;
        denp[nf] += v[r];
      }
      const int wb0 = (mw * 16 + g * 4) * 2;
      *(f16x2*)(sbase + fl * 128 + ((wb0 + 0) ^ sw)) = pack_f16(v[0], v[1]);
      *(f16x2*)(sbase + fl * 128 + ((wb0 + 4) ^ sw)) = pack_f16(v[2], v[3]);
    }
  }

  // ---- second GEMM: num[32f][16e] over this wave's 64 w
  f32x4 numT[2];
#pragma unroll
  for (int nf = 0; nf < 2; ++nf) numT[nf] = (f32x4){0.f, 0.f, 0.f, 0.f};
#pragma unroll
  for (int kstep = 0; kstep < 2; ++kstep) {
    const f16x8 hb = (kstep == 0) ? hb0 : hb1;
#pragma unroll
    for (int nf = 0; nf < 2; ++nf) {
      const int fl = nf * 16 + lrow;
      const int sw = (fl & 7) << 4;
      const f16x8 scf =
          *(const f16x8*)(sbase + fl * 128 + ((kstep * 64 + g * 16) ^ sw));
      numT[nf] =
          __builtin_amdgcn_mfma_f32_16x16x32_f16(scf, hb, numT[nf], 0, 0, 0);
    }
  }

  // ---- den: sum across the 4 lane-groups (same f, different g)
#pragma unroll
  for (int nf = 0; nf < 2; ++nf) {
    denp[nf] += __shfl_xor(denp[nf], 16, 64);
    denp[nf] += __shfl_xor(denp[nf], 32, 64);
  }

  // ---- accumulate global num/den with HW fp atomics
  if (lane < 16) {
#pragma unroll
    for (int nf = 0; nf < 2; ++nf)
      unsafeAtomicAdd(&den[fbase + nf * 16 + lrow], denp[nf]);
  }
#pragma unroll
  for (int nf = 0; nf < 2; ++nf)
#pragma unroll
    for (int r = 0; r < 4; ++r) {
      const int f = fbase + nf * 16 + g * 4 + r;
      unsafeAtomicAdd(&num[(size_t)f * Edim + lrow], numT[nf][r]);
    }
}

// out[b][e] = sum_f values[b][f] * num[f][e] / den[f]  (division inline)
__global__ __launch_bounds__(256) void out_gemv_kernel(
    const float* __restrict__ values, const float* __restrict__ num,
    const float* __restrict__ den, float* __restrict__ out) {
  const int b = blockIdx.x, tid = threadIdx.x;
  float acc[Edim];
#pragma unroll
  for (int e = 0; e < Edim; ++e) acc[e] = 0.f;
  for (int f = tid; f < Fdim; f += 256) {
    float v = values[b * Fdim + f] * fast_rcp(den[f]);
    const float4* c4 = (const float4*)(num + (size_t)f * Edim);
    float4 c0 = c4[0], c1 = c4[1], c2 = c4[2], c3 = c4[3];
    float cr[Edim] = {c0.x, c0.y, c0.z, c0.w, c1.x, c1.y, c1.z, c1.w,
                      c2.x, c2.y, c2.z, c2.w, c3.x, c3.y, c3.z, c3.w};
#pragma unroll
    for (int e = 0; e < Edim; ++e) acc[e] = fmaf(v, cr[e], acc[e]);
  }
  __shared__ float s_red[4][Edim];
  const int lane = tid & 63, wv = tid >> 6;
#pragma unroll
  for (int e = 0; e < Edim; ++e) {
    float a = wave64_sum(acc[e]);
    if (lane == 63) s_red[wv][e] = a;
  }
  __syncthreads();
  if (tid < Edim)
    out[b * Edim + tid] =
        s_red[0][tid] + s_red[1][tid] + s_red[2][tid] + s_red[3][tid];
}

extern "C" void kernel_launch(void* const* d_in, const int* in_sizes, int n_in,
                              void* d_out, int out_size, void* d_ws,
                              size_t ws_size, hipStream_t stream) {
  const float* values = (const float*)d_in[0];
  const float* femb   = (const float*)d_in[1];
  const float* hemb   = (const float*)d_in[2];
  const float* Ww     = (const float*)d_in[3];
  const float* bw     = (const float*)d_in[4];
  const float* Wu     = (const float*)d_in[5];
  const unsigned char* mask = (const unsigned char*)d_in[6];
  float* out = (float*)d_out;
  float* ws = (float*)d_ws;

  // ws layout (float units). Total ~3.7 MB.
  const size_t OFF_A = 16;                                // 128*6*512 f16
  const size_t OFF_B = OFF_A + (size_t)128 * NKS * 256;   // 256*6*512 f16
  const size_t OFF_HB = OFF_B + (size_t)256 * NKS * 256;  // 32768 f
  const size_t OFF_MB = OFF_HB + 32768;                   // Mp*NWRD u32
  const size_t OFF_PN = OFF_MB + (size_t)Mp * NWRD;       // num Mp*Edim
  const size_t OFF_PD = OFF_PN + (size_t)Mp * Edim;       // den Mp

  _Float16* A2 = (_Float16*)(ws + OFF_A);
  _Float16* B2 = (_Float16*)(ws + OFF_B);
  _Float16* hembB = (_Float16*)(ws + OFF_HB);
  unsigned int* mbits = (unsigned int*)(ws + OFF_MB);
  float* num = ws + OFF_PN;
  float* den = ws + OFF_PD;

  constexpr int PTOT = 128 * NKS * 64 + 256 * NKS * 64 + Mp * NWRD +
                       (Np / 32) * 64 + Mp * Edim + Mp;  // 452608 -> 1768
  prep2_kernel<<<dim3(PTOT / 256), dim3(256), 0, stream>>>(
      femb, hemb, Ww, bw, Wu, mask, A2, B2, mbits, hembB, num);

  score_ctx_kernel<<<dim3(32, 32), dim3(256), 0, stream>>>(
      A2, B2, mbits, hembB, num, den);

  out_gemv_kernel<<<dim3(Bdim), dim3(256), 0, stream>>>(values, num, den, out);
}

// Round 21
// 33.743 us; speedup vs baseline: 2.8793x; 1.2449x over previous
//
#include <hip/hip_runtime.h>

constexpr int Fdim = 2000;
constexpr int Wdim = 4000;
constexpr int Edim = 16;
constexpr int Hdim = 64;
constexpr int Bdim = 256;
constexpr float kLog2e = 1.4426950408889634f;

// ---- MFMA-path padded dims
constexpr int Mp = 2048;        // padded F
constexpr int Np = 4096;        // padded W
constexpr int NKS = 6;          // 192 / 32 k-steps (3 tanh powers x 64 h)

typedef _Float16 f16x8 __attribute__((ext_vector_type(8)));
typedef _Float16 f16x2 __attribute__((ext_vector_type(2)));
typedef float f32x4 __attribute__((ext_vector_type(4)));

__device__ __forceinline__ float fast_exp2(float x) {
#if __has_builtin(__builtin_amdgcn_exp2f)
  return __builtin_amdgcn_exp2f(x);
#else
  return exp2f(x);
#endif
}
__device__ __forceinline__ float fast_rcp(float x) {
#if __has_builtin(__builtin_amdgcn_rcpf)
  return __builtin_amdgcn_rcpf(x);
#else
  return 1.0f / x;
#endif
}
__device__ __forceinline__ float dev_tanh(float x) {
  return 1.0f - 2.0f * fast_rcp(fast_exp2(2.0f * kLog2e * x) + 1.0f);
}
__device__ __forceinline__ f16x2 pack_f16(float a, float b) {
  return __builtin_bit_cast(f16x2, __builtin_amdgcn_cvt_pkrtz(a, b));
}

// ---- DPP wave-64 sum (VALU pipe). Result valid in lane 63.
template <int CTRL>
__device__ __forceinline__ float dpp_part(float x) {
  return __int_as_float(
      __builtin_amdgcn_update_dpp(0, __float_as_int(x), CTRL, 0xF, 0xF, true));
}
__device__ __forceinline__ float wave64_sum(float x) {
  const float x0 = x;
  x += dpp_part<0x111>(x0);
  x += dpp_part<0x112>(x0);
  x += dpp_part<0x113>(x0);
  x += dpp_part<0x114>(x);
  x += dpp_part<0x118>(x);
  x += dpp_part<0x142>(x);
  x += dpp_part<0x143>(x);
  return x;
}

// prep2: one thread per output f16x8 for A2/B2 (contiguous 16B/lane stores).
// Series: tanh(s+t) ~= (p+q)(1-pq);  K = 3*64 = 192.
//   A2[(ftile*NKS+ks)*512 + lane*8 + i] = p(f, hb+i)^j
//   B2 likewise with Wu[h]*{q, 1-q^2, -q}; pads -> 0.
//   hembB: fragment-major hemb (fp16).
//   zero section: num[Mp*Edim] + den[Mp].
// (mbits relay REMOVED: score_ctx stages the raw mask itself.)
__global__ __launch_bounds__(256) void prep2_kernel(
    const float* __restrict__ femb, const float* __restrict__ hemb,
    const float* __restrict__ Ww, const float* __restrict__ bw,
    const float* __restrict__ Wu,
    _Float16* __restrict__ A2, _Float16* __restrict__ B2,
    _Float16* __restrict__ hembB, float* __restrict__ numden) {
  constexpr int PAV = 128 * NKS * 64;        // 49152  A2 vectors (192 blocks)
  constexpr int PBV = PAV + 256 * NKS * 64;  // 147456 B2 vectors (384)
  constexpr int PH = PBV + (Np / 32) * 64;   // 155648 hembB (32)
  constexpr int PZ = PH + Mp * Edim + Mp;    // 190464 zero num+den (136)
  int idx = blockIdx.x * 256 + threadIdx.x;
  if (idx < PAV) {
    const int lane = idx & 63, rest = idx >> 6;
    const int ks = rest % NKS, ftile = rest / NKS;
    const int f = ftile * 16 + (lane & 15);
    const int k0 = ks * 32 + (lane >> 4) * 8;
    const int j = k0 >> 6, hb = k0 & 63;
    f16x8 o;
    if (f < Fdim) {
      float s8[8] = {0.f, 0.f, 0.f, 0.f, 0.f, 0.f, 0.f, 0.f};
#pragma unroll
      for (int e = 0; e < Edim; ++e) {
        const float fe = femb[f * Edim + e];
        const float* wr = Ww + e * Hdim + hb;
#pragma unroll
        for (int i = 0; i < 8; ++i) s8[i] = fmaf(fe, wr[i], s8[i]);
      }
#pragma unroll
      for (int i = 0; i < 8; ++i) {
        float p = dev_tanh(s8[i]);
        float pj = (j == 0) ? 1.f : (j == 1) ? p : p * p;
        o[i] = (_Float16)pj;
      }
    } else {
#pragma unroll
      for (int i = 0; i < 8; ++i) o[i] = (_Float16)0.f;
    }
    *(f16x8*)(A2 + (size_t)idx * 8) = o;
  } else if (idx < PBV) {
    const int v = idx - PAV;
    const int lane = v & 63, rest = v >> 6;
    const int ks = rest % NKS, wtile = rest / NKS;
    const int w = wtile * 16 + (lane & 15);
    const int k0 = ks * 32 + (lane >> 4) * 8;
    const int j = k0 >> 6, hb = k0 & 63;
    f16x8 o;
    if (w < Wdim) {
      float t8[8];
#pragma unroll
      for (int i = 0; i < 8; ++i) t8[i] = bw[hb + i];
#pragma unroll
      for (int e = 0; e < Edim; ++e) {
        const float he = hemb[(size_t)w * Edim + e];
        const float* wr = Ww + (Edim + e) * Hdim + hb;
#pragma unroll
        for (int i = 0; i < 8; ++i) t8[i] = fmaf(he, wr[i], t8[i]);
      }
#pragma unroll
      for (int i = 0; i < 8; ++i) {
        float q = dev_tanh(t8[i]);
        float val = (j == 0) ? q : (j == 1) ? (1.f - q * q) : -q;
        o[i] = (_Float16)(Wu[hb + i] * val);
      }
    } else {
#pragma unroll
      for (int i = 0; i < 8; ++i) o[i] = (_Float16)0.f;
    }
    *(f16x8*)(B2 + (size_t)v * 8) = o;
  } else if (idx < PH) {
    int j = idx - PBV;
    int lane = j & 63;
    int e = lane & 15;
    int wb = (j >> 6) * 32 + (lane >> 4) * 8;
    f16x8 v;
#pragma unroll
    for (int i = 0; i < 8; ++i) {
      int w = wb + i;
      v[i] = (w < Wdim) ? (_Float16)hemb[(size_t)w * Edim + e] : (_Float16)0.f;
    }
    *(f16x8*)(hembB + (size_t)j * 8) = v;
  } else if (idx < PZ) {
    numden[idx - PH] = 0.f;
  }
}

// score_ctx: fused, 32f x 64w per wave, 1024 blocks, XCD-swizzled.
// Stages its own 64f x 128w mask tile into LDS (coalesced uint4 rows,
// XOR-swizzled 16B tiles; all-or-nothing guards since Wdim%16==0), issued
// BEFORE GEMM1 so the load latency hides under 48 MFMAs. 256-byte ballot
// probe resolves byte/int32 layout per block.
// First GEMM SWAPPED: mfma(B_w, A_f) -> D col=f, row=w. Epilogue:
// exp2 * mask(LDS) -> fp16 -> per-wave swizzled sc tile. Second GEMM
// contracts w -> num[32f][16e]; HW fp32 atomics accumulate.
__global__ __launch_bounds__(256) void score_ctx_kernel(
    const _Float16* __restrict__ A2, const _Float16* __restrict__ B2,
    const unsigned char* __restrict__ mask_b, const _Float16* __restrict__ hembB,
    float* __restrict__ num, float* __restrict__ den) {
  __shared__ __align__(16) char smem[16384 + 8192 + 16];
  char* M_base = smem + 16384;          // 8KB mask tile [64f][128w] bytes
  int* s_any = (int*)(smem + 24576);

  const int tid = threadIdx.x;
  const int wid = tid >> 6, lane = tid & 63;
  const int wr = wid >> 1, wc = wid & 1;

  // ---- bijective XCD swizzle (1024 blocks, 8 XCDs)
  const int lin = blockIdx.y * 32 + blockIdx.x;   // grid (32, 32)
  const int nl = (lin & 7) * 128 + (lin >> 3);
  const int bx = nl >> 5;   // w-tile (128 w) index [0,32)
  const int by = nl & 31;   // f-tile (64 f) index [0,32)

  const int fblk = by * 64;
  const int wblk = bx * 128;
  const int fbase = fblk + wr * 32;      // wave owns 32 f
  const int wbase = wblk + wc * 64;      // wave owns 64 w
  const int lrow = lane & 15, g = lane >> 4;

  // ---- mask layout probe (256B; byte layout has random 0/1 at i%4!=0,
  // int32 layout has exact zeros there; P[miss] = 2^-192)
  if (tid == 0) *s_any = 0;
  __syncthreads();
  if ((tid & 3) && mask_b[tid]) atomicOr(s_any, 1);
  __syncthreads();
  const int mbyte = *s_any;  // 1 = byte layout, 0 = int32

  // ---- stage mask tile -> LDS (swizzled; issued before GEMM1)
  if (mbyte) {
    // 64 rows x 128 B = 512 uint4
#pragma unroll
    for (int it = 0; it < 2; ++it) {
      const int t = it * 256 + tid;
      const int row = t >> 3, c16 = t & 7;
      const int f = fblk + row;
      const int w0 = wblk + c16 * 16;
      uint4 mv = make_uint4(0u, 0u, 0u, 0u);
      if (f < Fdim && w0 < Wdim)
        mv = *(const uint4*)(mask_b + (size_t)f * Wdim + w0);
      *(uint4*)(M_base + row * 128 + ((c16 * 16) ^ ((row & 7) << 4))) = mv;
    }
  } else {
    // 64 rows x 128 ints; uint4 = 4 ints -> 4 bytes
    const int* mask_i = (const int*)mask_b;
#pragma unroll
    for (int it = 0; it < 8; ++it) {
      const int t = it * 256 + tid;
      const int row = t >> 5, c4 = t & 31;
      const int f = fblk + row;
      const int w0 = wblk + c4 * 4;
      unsigned int pk = 0u;
      if (f < Fdim && w0 < Wdim) {
        uint4 mi = *(const uint4*)(mask_i + (size_t)f * Wdim + w0);
        pk = (mi.x ? 1u : 0u) | (mi.y ? 1u : 0u) << 8 |
             (mi.z ? 1u : 0u) << 16 | (mi.w ? 1u : 0u) << 24;
      }
      *(unsigned int*)(M_base + row * 128 + ((c4 * 4) ^ ((row & 7) << 4))) = pk;
    }
  }

  // ---- EARLY issue: hembB fragments
  const f16x8 hb0 =
      *(const f16x8*)(hembB + ((size_t)(wbase >> 5) + 0) * 512 + lane * 8);
  const f16x8 hb1 =
      *(const f16x8*)(hembB + ((size_t)(wbase >> 5) + 1) * 512 + lane * 8);

  // ---- first GEMM: accT[mw][nf] = sc^T frags (col=f, row=w)
  f32x4 accT[4][2];
#pragma unroll
  for (int mw = 0; mw < 4; ++mw)
#pragma unroll
    for (int nf = 0; nf < 2; ++nf) accT[mw][nf] = (f32x4){0.f, 0.f, 0.f, 0.f};

  const _Float16* Ab = A2 + ((size_t)(fbase >> 4) * NKS) * 512 + lane * 8;
  const _Float16* Bb = B2 + ((size_t)(wbase >> 4) * NKS) * 512 + lane * 8;
#pragma unroll 2
  for (int ks = 0; ks < NKS; ++ks) {
    f16x8 bw[4], af[2];
#pragma unroll
    for (int mw = 0; mw < 4; ++mw)
      bw[mw] = *(const f16x8*)(Bb + (size_t)(mw * NKS + ks) * 512);
#pragma unroll
    for (int nf = 0; nf < 2; ++nf)
      af[nf] = *(const f16x8*)(Ab + (size_t)(nf * NKS + ks) * 512);
#pragma unroll
    for (int mw = 0; mw < 4; ++mw)
#pragma unroll
      for (int nf = 0; nf < 2; ++nf)
        accT[mw][nf] = __builtin_amdgcn_mfma_f32_16x16x32_f16(
            bw[mw], af[nf], accT[mw][nf], 0, 0, 0);
  }
  __syncthreads();  // mask tile visible to all waves

  // ---- epilogue: exp2 * mask(LDS) -> fp16 -> swizzled sc; den partials
  char* sbase = smem + wid * 4096;
  float denp[2] = {0.f, 0.f};
#pragma unroll
  for (int nf = 0; nf < 2; ++nf) {
    const int flm = wr * 32 + nf * 16 + lrow;   // row in 64-f mask tile
    const int fl = nf * 16 + lrow;              // row in 32-f sc tile
    const int sw = (fl & 7) << 4;
    const int swm = (flm & 7) << 4;
#pragma unroll
    for (int mw = 0; mw < 4; ++mw) {
      const unsigned int u = *(const unsigned int*)(
          M_base + flm * 128 + ((wc * 64 + mw * 16 + g * 4) ^ swm));
      float v[4];
#pragma unroll
      for (int r = 0; r < 4; ++r) {
        const float m = ((u >> (8 * r)) & 0xFFu) ? 1.f : 0.f;
        v[r] = fast_exp2(accT[mw][nf][r] * kLog2e) * m;
        denp[nf] += v[r];
      }
      const int wb0 = (mw * 16 + g * 4) * 2;
      *(f16x2*)(sbase + fl * 128 + ((wb0 + 0) ^ sw)) = pack_f16(v[0], v[1]);
      *(f16x2*)(sbase + fl * 128 + ((wb0 + 4) ^ sw)) = pack_f16(v[2], v[3]);
    }
  }

  // ---- second GEMM: num[32f][16e] over this wave's 64 w
  f32x4 numT[2];
#pragma unroll
  for (int nf = 0; nf < 2; ++nf) numT[nf] = (f32x4){0.f, 0.f, 0.f, 0.f};
#pragma unroll
  for (int kstep = 0; kstep < 2; ++kstep) {
    const f16x8 hb = (kstep == 0) ? hb0 : hb1;
#pragma unroll
    for (int nf = 0; nf < 2; ++nf) {
      const int fl = nf * 16 + lrow;
      const int sw = (fl & 7) << 4;
      const f16x8 scf =
          *(const f16x8*)(sbase + fl * 128 + ((kstep * 64 + g * 16) ^ sw));
      numT[nf] =
          __builtin_amdgcn_mfma_f32_16x16x32_f16(scf, hb, numT[nf], 0, 0, 0);
    }
  }

  // ---- den: sum across the 4 lane-groups (same f, different g)
#pragma unroll
  for (int nf = 0; nf < 2; ++nf) {
    denp[nf] += __shfl_xor(denp[nf], 16, 64);
    denp[nf] += __shfl_xor(denp[nf], 32, 64);
  }

  // ---- accumulate global num/den with HW fp atomics
  if (lane < 16) {
#pragma unroll
    for (int nf = 0; nf < 2; ++nf)
      unsafeAtomicAdd(&den[fbase + nf * 16 + lrow], denp[nf]);
  }
#pragma unroll
  for (int nf = 0; nf < 2; ++nf)
#pragma unroll
    for (int r = 0; r < 4; ++r) {
      const int f = fbase + nf * 16 + g * 4 + r;
      unsafeAtomicAdd(&num[(size_t)f * Edim + lrow], numT[nf][r]);
    }
}

// out[b][e] = sum_f values[b][f] * num[f][e] / den[f]  (division inline)
__global__ __launch_bounds__(256) void out_gemv_kernel(
    const float* __restrict__ values, const float* __restrict__ num,
    const float* __restrict__ den, float* __restrict__ out) {
  const int b = blockIdx.x, tid = threadIdx.x;
  float acc[Edim];
#pragma unroll
  for (int e = 0; e < Edim; ++e) acc[e] = 0.f;
  for (int f = tid; f < Fdim; f += 256) {
    float v = values[b * Fdim + f] * fast_rcp(den[f]);
    const float4* c4 = (const float4*)(num + (size_t)f * Edim);
    float4 c0 = c4[0], c1 = c4[1], c2 = c4[2], c3 = c4[3];
    float cr[Edim] = {c0.x, c0.y, c0.z, c0.w, c1.x, c1.y, c1.z, c1.w,
                      c2.x, c2.y, c2.z, c2.w, c3.x, c3.y, c3.z, c3.w};
#pragma unroll
    for (int e = 0; e < Edim; ++e) acc[e] = fmaf(v, cr[e], acc[e]);
  }
  __shared__ float s_red[4][Edim];
  const int lane = tid & 63, wv = tid >> 6;
#pragma unroll
  for (int e = 0; e < Edim; ++e) {
    float a = wave64_sum(acc[e]);
    if (lane == 63) s_red[wv][e] = a;
  }
  __syncthreads();
  if (tid < Edim)
    out[b * Edim + tid] =
        s_red[0][tid] + s_red[1][tid] + s_red[2][tid] + s_red[3][tid];
}

extern "C" void kernel_launch(void* const* d_in, const int* in_sizes, int n_in,
                              void* d_out, int out_size, void* d_ws,
                              size_t ws_size, hipStream_t stream) {
  const float* values = (const float*)d_in[0];
  const float* femb   = (const float*)d_in[1];
  const float* hemb   = (const float*)d_in[2];
  const float* Ww     = (const float*)d_in[3];
  const float* bw     = (const float*)d_in[4];
  const float* Wu     = (const float*)d_in[5];
  const unsigned char* mask = (const unsigned char*)d_in[6];
  float* out = (float*)d_out;
  float* ws = (float*)d_ws;

  // ws layout (float units). Total ~2.7 MB.
  const size_t OFF_A = 16;                                // 128*6*512 f16
  const size_t OFF_B = OFF_A + (size_t)128 * NKS * 256;   // 256*6*512 f16
  const size_t OFF_HB = OFF_B + (size_t)256 * NKS * 256;  // 32768 f
  const size_t OFF_PN = OFF_HB + 32768;                   // num Mp*Edim
  const size_t OFF_PD = OFF_PN + (size_t)Mp * Edim;       // den Mp

  _Float16* A2 = (_Float16*)(ws + OFF_A);
  _Float16* B2 = (_Float16*)(ws + OFF_B);
  _Float16* hembB = (_Float16*)(ws + OFF_HB);
  float* num = ws + OFF_PN;
  float* den = ws + OFF_PD;

  constexpr int PTOT = 128 * NKS * 64 + 256 * NKS * 64 + (Np / 32) * 64 +
                       Mp * Edim + Mp;  // 190464 -> 744 blocks
  prep2_kernel<<<dim3(PTOT / 256), dim3(256), 0, stream>>>(
      femb, hemb, Ww, bw, Wu, A2, B2, hembB, num);

  score_ctx_kernel<<<dim3(32, 32), dim3(256), 0, stream>>>(
      A2, B2, mask, hembB, num, den);

  out_gemv_kernel<<<dim3(Bdim), dim3(256), 0, stream>>>(values, num, den, out);
}

// Round 22
// 33.270 us; speedup vs baseline: 2.9202x; 1.0142x over previous
//
#include <hip/hip_runtime.h>

constexpr int Fdim = 2000;
constexpr int Wdim = 4000;
constexpr int Edim = 16;
constexpr int Hdim = 64;
constexpr int Bdim = 256;
constexpr float kLog2e = 1.4426950408889634f;

// ---- MFMA-path padded dims
constexpr int Mp = 2048;        // padded F
constexpr int Np = 4096;        // padded W
constexpr int NKS = 6;          // 192 / 32 k-steps (3 tanh powers x 64 h)
constexpr int FSPLIT = 4;       // gemv f-chunks
constexpr int FCH = Fdim / FSPLIT;  // 500

typedef _Float16 f16x8 __attribute__((ext_vector_type(8)));
typedef _Float16 f16x2 __attribute__((ext_vector_type(2)));
typedef float f32x4 __attribute__((ext_vector_type(4)));

__device__ __forceinline__ float fast_exp2(float x) {
#if __has_builtin(__builtin_amdgcn_exp2f)
  return __builtin_amdgcn_exp2f(x);
#else
  return exp2f(x);
#endif
}
__device__ __forceinline__ float fast_rcp(float x) {
#if __has_builtin(__builtin_amdgcn_rcpf)
  return __builtin_amdgcn_rcpf(x);
#else
  return 1.0f / x;
#endif
}
__device__ __forceinline__ float dev_tanh(float x) {
  return 1.0f - 2.0f * fast_rcp(fast_exp2(2.0f * kLog2e * x) + 1.0f);
}
__device__ __forceinline__ f16x2 pack_f16(float a, float b) {
  return __builtin_bit_cast(f16x2, __builtin_amdgcn_cvt_pkrtz(a, b));
}

// ---- DPP wave-64 sum (VALU pipe). Result valid in lane 63.
template <int CTRL>
__device__ __forceinline__ float dpp_part(float x) {
  return __int_as_float(
      __builtin_amdgcn_update_dpp(0, __float_as_int(x), CTRL, 0xF, 0xF, true));
}
__device__ __forceinline__ float wave64_sum(float x) {
  const float x0 = x;
  x += dpp_part<0x111>(x0);
  x += dpp_part<0x112>(x0);
  x += dpp_part<0x113>(x0);
  x += dpp_part<0x114>(x);
  x += dpp_part<0x118>(x);
  x += dpp_part<0x142>(x);
  x += dpp_part<0x143>(x);
  return x;
}

// prep2: one thread per output f16x8 for A2/B2 (contiguous 16B/lane stores;
// femb/hemb rows loaded as 4x float4). Series: tanh(s+t) ~= (p+q)(1-pq).
//   A2[(ftile*NKS+ks)*512 + lane*8 + i] = p(f, hb+i)^j
//   B2 likewise with Wu[h]*{q, 1-q^2, -q}; pads -> 0.
//   hembB: fragment-major hemb (fp16).
//   zero sections: num[Mp*Edim]+den[Mp], then out[Bdim*Edim].
__global__ __launch_bounds__(256) void prep2_kernel(
    const float* __restrict__ femb, const float* __restrict__ hemb,
    const float* __restrict__ Ww, const float* __restrict__ bw,
    const float* __restrict__ Wu,
    _Float16* __restrict__ A2, _Float16* __restrict__ B2,
    _Float16* __restrict__ hembB, float* __restrict__ numden,
    float* __restrict__ outz) {
  constexpr int PAV = 128 * NKS * 64;        // 49152  A2 vectors (192 blocks)
  constexpr int PBV = PAV + 256 * NKS * 64;  // 147456 B2 vectors (384)
  constexpr int PH = PBV + (Np / 32) * 64;   // 155648 hembB (32)
  constexpr int PZ = PH + Mp * Edim + Mp;    // 190464 zero num+den (136)
  constexpr int PO = PZ + Bdim * Edim;       // 194560 zero out (16)
  int idx = blockIdx.x * 256 + threadIdx.x;
  if (idx < PAV) {
    const int lane = idx & 63, rest = idx >> 6;
    const int ks = rest % NKS, ftile = rest / NKS;
    const int f = ftile * 16 + (lane & 15);
    const int k0 = ks * 32 + (lane >> 4) * 8;
    const int j = k0 >> 6, hb = k0 & 63;
    f16x8 o;
    if (f < Fdim) {
      float s8[8] = {0.f, 0.f, 0.f, 0.f, 0.f, 0.f, 0.f, 0.f};
      const float4* fr = (const float4*)(femb + (size_t)f * Edim);
      float4 fq[4] = {fr[0], fr[1], fr[2], fr[3]};
      const float* fe = (const float*)fq;
#pragma unroll
      for (int e = 0; e < Edim; ++e) {
        const float* wr = Ww + e * Hdim + hb;
#pragma unroll
        for (int i = 0; i < 8; ++i) s8[i] = fmaf(fe[e], wr[i], s8[i]);
      }
#pragma unroll
      for (int i = 0; i < 8; ++i) {
        float p = dev_tanh(s8[i]);
        float pj = (j == 0) ? 1.f : (j == 1) ? p : p * p;
        o[i] = (_Float16)pj;
      }
    } else {
#pragma unroll
      for (int i = 0; i < 8; ++i) o[i] = (_Float16)0.f;
    }
    *(f16x8*)(A2 + (size_t)idx * 8) = o;
  } else if (idx < PBV) {
    const int v = idx - PAV;
    const int lane = v & 63, rest = v >> 6;
    const int ks = rest % NKS, wtile = rest / NKS;
    const int w = wtile * 16 + (lane & 15);
    const int k0 = ks * 32 + (lane >> 4) * 8;
    const int j = k0 >> 6, hb = k0 & 63;
    f16x8 o;
    if (w < Wdim) {
      float t8[8];
#pragma unroll
      for (int i = 0; i < 8; ++i) t8[i] = bw[hb + i];
      const float4* hr = (const float4*)(hemb + (size_t)w * Edim);
      float4 hq[4] = {hr[0], hr[1], hr[2], hr[3]};
      const float* he = (const float*)hq;
#pragma unroll
      for (int e = 0; e < Edim; ++e) {
        const float* wr = Ww + (Edim + e) * Hdim + hb;
#pragma unroll
        for (int i = 0; i < 8; ++i) t8[i] = fmaf(he[e], wr[i], t8[i]);
      }
#pragma unroll
      for (int i = 0; i < 8; ++i) {
        float q = dev_tanh(t8[i]);
        float val = (j == 0) ? q : (j == 1) ? (1.f - q * q) : -q;
        o[i] = (_Float16)(Wu[hb + i] * val);
      }
    } else {
#pragma unroll
      for (int i = 0; i < 8; ++i) o[i] = (_Float16)0.f;
    }
    *(f16x8*)(B2 + (size_t)v * 8) = o;
  } else if (idx < PH) {
    int j = idx - PBV;
    int lane = j & 63;
    int e = lane & 15;
    int wb = (j >> 6) * 32 + (lane >> 4) * 8;
    f16x8 v;
#pragma unroll
    for (int i = 0; i < 8; ++i) {
      int w = wb + i;
      v[i] = (w < Wdim) ? (_Float16)hemb[(size_t)w * Edim + e] : (_Float16)0.f;
    }
    *(f16x8*)(hembB + (size_t)j * 8) = v;
  } else if (idx < PZ) {
    numden[idx - PH] = 0.f;
  } else if (idx < PO) {
    outz[idx - PZ] = 0.f;
  }
}

// score_ctx: fused, 32f x 64w per wave, 1024 blocks, XCD-swizzled.
// Stages its own 64f x 128w mask tile into LDS (coalesced, XOR-swizzled),
// issued BEFORE GEMM1. 256-byte ballot probe resolves byte/int32 layout.
// First GEMM SWAPPED: mfma(B_w, A_f) -> D col=f, row=w. Epilogue:
// exp2 * mask(LDS) -> fp16 -> per-wave swizzled sc tile. Second GEMM
// contracts w -> num[32f][16e]; HW fp32 atomics accumulate.
__global__ __launch_bounds__(256) void score_ctx_kernel(
    const _Float16* __restrict__ A2, const _Float16* __restrict__ B2,
    const unsigned char* __restrict__ mask_b, const _Float16* __restrict__ hembB,
    float* __restrict__ num, float* __restrict__ den) {
  __shared__ __align__(16) char smem[16384 + 8192 + 16];
  char* M_base = smem + 16384;          // 8KB mask tile [64f][128w] bytes
  int* s_any = (int*)(smem + 24576);

  const int tid = threadIdx.x;
  const int wid = tid >> 6, lane = tid & 63;
  const int wr = wid >> 1, wc = wid & 1;

  // ---- bijective XCD swizzle (1024 blocks, 8 XCDs)
  const int lin = blockIdx.y * 32 + blockIdx.x;   // grid (32, 32)
  const int nl = (lin & 7) * 128 + (lin >> 3);
  const int bx = nl >> 5;   // w-tile (128 w) index [0,32)
  const int by = nl & 31;   // f-tile (64 f) index [0,32)

  const int fblk = by * 64;
  const int wblk = bx * 128;
  const int fbase = fblk + wr * 32;      // wave owns 32 f
  const int wbase = wblk + wc * 64;      // wave owns 64 w
  const int lrow = lane & 15, g = lane >> 4;

  // ---- mask layout probe (256B; int32 layout has exact zeros at i%4!=0)
  if (tid == 0) *s_any = 0;
  __syncthreads();
  if ((tid & 3) && mask_b[tid]) atomicOr(s_any, 1);
  __syncthreads();
  const int mbyte = *s_any;  // 1 = byte layout, 0 = int32

  // ---- stage mask tile -> LDS (swizzled; issued before GEMM1)
  if (mbyte) {
#pragma unroll
    for (int it = 0; it < 2; ++it) {
      const int t = it * 256 + tid;
      const int row = t >> 3, c16 = t & 7;
      const int f = fblk + row;
      const int w0 = wblk + c16 * 16;
      uint4 mv = make_uint4(0u, 0u, 0u, 0u);
      if (f < Fdim && w0 < Wdim)
        mv = *(const uint4*)(mask_b + (size_t)f * Wdim + w0);
      *(uint4*)(M_base + row * 128 + ((c16 * 16) ^ ((row & 7) << 4))) = mv;
    }
  } else {
    const int* mask_i = (const int*)mask_b;
#pragma unroll
    for (int it = 0; it < 8; ++it) {
      const int t = it * 256 + tid;
      const int row = t >> 5, c4 = t & 31;
      const int f = fblk + row;
      const int w0 = wblk + c4 * 4;
      unsigned int pk = 0u;
      if (f < Fdim && w0 < Wdim) {
        uint4 mi = *(const uint4*)(mask_i + (size_t)f * Wdim + w0);
        pk = (mi.x ? 1u : 0u) | (mi.y ? 1u : 0u) << 8 |
             (mi.z ? 1u : 0u) << 16 | (mi.w ? 1u : 0u) << 24;
      }
      *(unsigned int*)(M_base + row * 128 + ((c4 * 4) ^ ((row & 7) << 4))) = pk;
    }
  }

  // ---- EARLY issue: hembB fragments
  const f16x8 hb0 =
      *(const f16x8*)(hembB + ((size_t)(wbase >> 5) + 0) * 512 + lane * 8);
  const f16x8 hb1 =
      *(const f16x8*)(hembB + ((size_t)(wbase >> 5) + 1) * 512 + lane * 8);

  // ---- first GEMM: accT[mw][nf] = sc^T frags (col=f, row=w)
  f32x4 accT[4][2];
#pragma unroll
  for (int mw = 0; mw < 4; ++mw)
#pragma unroll
    for (int nf = 0; nf < 2; ++nf) accT[mw][nf] = (f32x4){0.f, 0.f, 0.f, 0.f};

  const _Float16* Ab = A2 + ((size_t)(fbase >> 4) * NKS) * 512 + lane * 8;
  const _Float16* Bb = B2 + ((size_t)(wbase >> 4) * NKS) * 512 + lane * 8;
#pragma unroll 2
  for (int ks = 0; ks < NKS; ++ks) {
    f16x8 bw[4], af[2];
#pragma unroll
    for (int mw = 0; mw < 4; ++mw)
      bw[mw] = *(const f16x8*)(Bb + (size_t)(mw * NKS + ks) * 512);
#pragma unroll
    for (int nf = 0; nf < 2; ++nf)
      af[nf] = *(const f16x8*)(Ab + (size_t)(nf * NKS + ks) * 512);
#pragma unroll
    for (int mw = 0; mw < 4; ++mw)
#pragma unroll
      for (int nf = 0; nf < 2; ++nf)
        accT[mw][nf] = __builtin_amdgcn_mfma_f32_16x16x32_f16(
            bw[mw], af[nf], accT[mw][nf], 0, 0, 0);
  }
  __syncthreads();  // mask tile visible to all waves

  // ---- epilogue: exp2 * mask(LDS) -> fp16 -> swizzled sc; den partials
  char* sbase = smem + wid * 4096;
  float denp[2] = {0.f, 0.f};
#pragma unroll
  for (int nf = 0; nf < 2; ++nf) {
    const int flm = wr * 32 + nf * 16 + lrow;   // row in 64-f mask tile
    const int fl = nf * 16 + lrow;              // row in 32-f sc tile
    const int sw = (fl & 7) << 4;
    const int swm = (flm & 7) << 4;
#pragma unroll
    for (int mw = 0; mw < 4; ++mw) {
      const unsigned int u = *(const unsigned int*)(
          M_base + flm * 128 + ((wc * 64 + mw * 16 + g * 4) ^ swm));
      float v[4];
#pragma unroll
      for (int r = 0; r < 4; ++r) {
        const float m = ((u >> (8 * r)) & 0xFFu) ? 1.f : 0.f;
        v[r] = fast_exp2(accT[mw][nf][r] * kLog2e) * m;
        denp[nf] += v[r];
      }
      const int wb0 = (mw * 16 + g * 4) * 2;
      *(f16x2*)(sbase + fl * 128 + ((wb0 + 0) ^ sw)) = pack_f16(v[0], v[1]);
      *(f16x2*)(sbase + fl * 128 + ((wb0 + 4) ^ sw)) = pack_f16(v[2], v[3]);
    }
  }

  // ---- second GEMM: num[32f][16e] over this wave's 64 w
  f32x4 numT[2];
#pragma unroll
  for (int nf = 0; nf < 2; ++nf) numT[nf] = (f32x4){0.f, 0.f, 0.f, 0.f};
#pragma unroll
  for (int kstep = 0; kstep < 2; ++kstep) {
    const f16x8 hb = (kstep == 0) ? hb0 : hb1;
#pragma unroll
    for (int nf = 0; nf < 2; ++nf) {
      const int fl = nf * 16 + lrow;
      const int sw = (fl & 7) << 4;
      const f16x8 scf =
          *(const f16x8*)(sbase + fl * 128 + ((kstep * 64 + g * 16) ^ sw));
      numT[nf] =
          __builtin_amdgcn_mfma_f32_16x16x32_f16(scf, hb, numT[nf], 0, 0, 0);
    }
  }

  // ---- den: sum across the 4 lane-groups (same f, different g)
#pragma unroll
  for (int nf = 0; nf < 2; ++nf) {
    denp[nf] += __shfl_xor(denp[nf], 16, 64);
    denp[nf] += __shfl_xor(denp[nf], 32, 64);
  }

  // ---- accumulate global num/den with HW fp atomics
  if (lane < 16) {
#pragma unroll
    for (int nf = 0; nf < 2; ++nf)
      unsafeAtomicAdd(&den[fbase + nf * 16 + lrow], denp[nf]);
  }
#pragma unroll
  for (int nf = 0; nf < 2; ++nf)
#pragma unroll
    for (int r = 0; r < 4; ++r) {
      const int f = fbase + nf * 16 + g * 4 + r;
      unsafeAtomicAdd(&num[(size_t)f * Edim + lrow], numT[nf][r]);
    }
}

// out[b][e] += sum_{f in chunk} values[b][f] * num[f][e] / den[f]
// grid (Bdim, FSPLIT); out zeroed by prep2; fp32 atomics accumulate.
__global__ __launch_bounds__(256) void out_gemv_kernel(
    const float* __restrict__ values, const float* __restrict__ num,
    const float* __restrict__ den, float* __restrict__ out) {
  const int b = blockIdx.x, tid = threadIdx.x;
  const int f0 = blockIdx.y * FCH;
  float acc[Edim];
#pragma unroll
  for (int e = 0; e < Edim; ++e) acc[e] = 0.f;
  for (int f = f0 + tid; f < f0 + FCH; f += 256) {
    float v = values[b * Fdim + f] * fast_rcp(den[f]);
    const float4* c4 = (const float4*)(num + (size_t)f * Edim);
    float4 c0 = c4[0], c1 = c4[1], c2 = c4[2], c3 = c4[3];
    float cr[Edim] = {c0.x, c0.y, c0.z, c0.w, c1.x, c1.y, c1.z, c1.w,
                      c2.x, c2.y, c2.z, c2.w, c3.x, c3.y, c3.z, c3.w};
#pragma unroll
    for (int e = 0; e < Edim; ++e) acc[e] = fmaf(v, cr[e], acc[e]);
  }
  __shared__ float s_red[4][Edim];
  const int lane = tid & 63, wv = tid >> 6;
#pragma unroll
  for (int e = 0; e < Edim; ++e) {
    float a = wave64_sum(acc[e]);
    if (lane == 63) s_red[wv][e] = a;
  }
  __syncthreads();
  if (tid < Edim) {
    float tot =
        s_red[0][tid] + s_red[1][tid] + s_red[2][tid] + s_red[3][tid];
    unsafeAtomicAdd(&out[b * Edim + tid], tot);
  }
}

extern "C" void kernel_launch(void* const* d_in, const int* in_sizes, int n_in,
                              void* d_out, int out_size, void* d_ws,
                              size_t ws_size, hipStream_t stream) {
  const float* values = (const float*)d_in[0];
  const float* femb   = (const float*)d_in[1];
  const float* hemb   = (const float*)d_in[2];
  const float* Ww     = (const float*)d_in[3];
  const float* bw     = (const float*)d_in[4];
  const float* Wu     = (const float*)d_in[5];
  const unsigned char* mask = (const unsigned char*)d_in[6];
  float* out = (float*)d_out;
  float* ws = (float*)d_ws;

  // ws layout (float units). Total ~2.7 MB.
  const size_t OFF_A = 16;                                // 128*6*512 f16
  const size_t OFF_B = OFF_A + (size_t)128 * NKS * 256;   // 256*6*512 f16
  const size_t OFF_HB = OFF_B + (size_t)256 * NKS * 256;  // 32768 f
  const size_t OFF_PN = OFF_HB + 32768;                   // num Mp*Edim
  const size_t OFF_PD = OFF_PN + (size_t)Mp * Edim;       // den Mp

  _Float16* A2 = (_Float16*)(ws + OFF_A);
  _Float16* B2 = (_Float16*)(ws + OFF_B);
  _Float16* hembB = (_Float16*)(ws + OFF_HB);
  float* num = ws + OFF_PN;
  float* den = ws + OFF_PD;

  constexpr int PTOT = 128 * NKS * 64 + 256 * NKS * 64 + (Np / 32) * 64 +
                       Mp * Edim + Mp + Bdim * Edim;  // 194560 -> 760 blocks
  prep2_kernel<<<dim3(PTOT / 256), dim3(256), 0, stream>>>(
      femb, hemb, Ww, bw, Wu, A2, B2, hembB, num, out);

  score_ctx_kernel<<<dim3(32, 32), dim3(256), 0, stream>>>(
      A2, B2, mask, hembB, num, den);

  out_gemv_kernel<<<dim3(Bdim, FSPLIT), dim3(256), 0, stream>>>(
      values, num, den, out);
}

// Round 24
// 33.202 us; speedup vs baseline: 2.9262x; 1.0020x over previous
//
#include <hip/hip_runtime.h>

constexpr int Fdim = 2000;
constexpr int Wdim = 4000;
constexpr int Edim = 16;
constexpr int Hdim = 64;
constexpr int Bdim = 256;
constexpr float kLog2e = 1.4426950408889634f;

// ---- MFMA-path padded dims
constexpr int Mp = 2048;        // padded F
constexpr int Np = 4096;        // padded W
constexpr int NKS = 6;          // 192 / 32 k-steps (3 tanh powers x 64 h)
constexpr int FSPLIT = 4;       // gemv f-chunks
constexpr int FCH = Fdim / FSPLIT;  // 500

typedef _Float16 f16x8 __attribute__((ext_vector_type(8)));
typedef _Float16 f16x2 __attribute__((ext_vector_type(2)));
typedef float f32x4 __attribute__((ext_vector_type(4)));

__device__ __forceinline__ float fast_exp2(float x) {
#if __has_builtin(__builtin_amdgcn_exp2f)
  return __builtin_amdgcn_exp2f(x);
#else
  return exp2f(x);
#endif
}
__device__ __forceinline__ float fast_rcp(float x) {
#if __has_builtin(__builtin_amdgcn_rcpf)
  return __builtin_amdgcn_rcpf(x);
#else
  return 1.0f / x;
#endif
}
__device__ __forceinline__ float dev_tanh(float x) {
  return 1.0f - 2.0f * fast_rcp(fast_exp2(2.0f * kLog2e * x) + 1.0f);
}
__device__ __forceinline__ f16x2 pack_f16(float a, float b) {
  return __builtin_bit_cast(f16x2, __builtin_amdgcn_cvt_pkrtz(a, b));
}

// ---- DPP wave-64 sum (VALU pipe). Result valid in lane 63.
template <int CTRL>
__device__ __forceinline__ float dpp_part(float x) {
  return __int_as_float(
      __builtin_amdgcn_update_dpp(0, __float_as_int(x), CTRL, 0xF, 0xF, true));
}
__device__ __forceinline__ float wave64_sum(float x) {
  const float x0 = x;
  x += dpp_part<0x111>(x0);
  x += dpp_part<0x112>(x0);
  x += dpp_part<0x113>(x0);
  x += dpp_part<0x114>(x);
  x += dpp_part<0x118>(x);
  x += dpp_part<0x142>(x);
  x += dpp_part<0x143>(x);
  return x;
}

// prep2: one thread per output f16x8 for A2/B2 (contiguous 16B/lane stores;
// femb/hemb rows loaded as 4x float4). Series: tanh(s+t) ~= (p+q)(1-pq).
//   A2[(ftile*NKS+ks)*512 + lane*8 + i] = p(f, hb+i)^j
//   B2 likewise with Wu[h]*{q, 1-q^2, -q}; pads -> 0.
//   hembB: fragment-major hemb (fp16).
//   zero sections: num[Mp*Edim]+den[Mp], then out[Bdim*Edim].
__global__ __launch_bounds__(256) void prep2_kernel(
    const float* __restrict__ femb, const float* __restrict__ hemb,
    const float* __restrict__ Ww, const float* __restrict__ bw,
    const float* __restrict__ Wu,
    _Float16* __restrict__ A2, _Float16* __restrict__ B2,
    _Float16* __restrict__ hembB, float* __restrict__ numden,
    float* __restrict__ outz) {
  constexpr int PAV = 128 * NKS * 64;        // 49152  A2 vectors (192 blocks)
  constexpr int PBV = PAV + 256 * NKS * 64;  // 147456 B2 vectors (384)
  constexpr int PH = PBV + (Np / 32) * 64;   // 155648 hembB (32)
  constexpr int PZ = PH + Mp * Edim + Mp;    // 190464 zero num+den (136)
  constexpr int PO = PZ + Bdim * Edim;       // 194560 zero out (16)
  int idx = blockIdx.x * 256 + threadIdx.x;
  if (idx < PAV) {
    const int lane = idx & 63, rest = idx >> 6;
    const int ks = rest % NKS, ftile = rest / NKS;
    const int f = ftile * 16 + (lane & 15);
    const int k0 = ks * 32 + (lane >> 4) * 8;
    const int j = k0 >> 6, hb = k0 & 63;
    f16x8 o;
    if (f < Fdim) {
      float s8[8] = {0.f, 0.f, 0.f, 0.f, 0.f, 0.f, 0.f, 0.f};
      const float4* fr = (const float4*)(femb + (size_t)f * Edim);
      float4 fq[4] = {fr[0], fr[1], fr[2], fr[3]};
      const float* fe = (const float*)fq;
#pragma unroll
      for (int e = 0; e < Edim; ++e) {
        const float* wr = Ww + e * Hdim + hb;
#pragma unroll
        for (int i = 0; i < 8; ++i) s8[i] = fmaf(fe[e], wr[i], s8[i]);
      }
#pragma unroll
      for (int i = 0; i < 8; ++i) {
        float p = dev_tanh(s8[i]);
        float pj = (j == 0) ? 1.f : (j == 1) ? p : p * p;
        o[i] = (_Float16)pj;
      }
    } else {
#pragma unroll
      for (int i = 0; i < 8; ++i) o[i] = (_Float16)0.f;
    }
    *(f16x8*)(A2 + (size_t)idx * 8) = o;
  } else if (idx < PBV) {
    const int v = idx - PAV;
    const int lane = v & 63, rest = v >> 6;
    const int ks = rest % NKS, wtile = rest / NKS;
    const int w = wtile * 16 + (lane & 15);
    const int k0 = ks * 32 + (lane >> 4) * 8;
    const int j = k0 >> 6, hb = k0 & 63;
    f16x8 o;
    if (w < Wdim) {
      float t8[8];
#pragma unroll
      for (int i = 0; i < 8; ++i) t8[i] = bw[hb + i];
      const float4* hr = (const float4*)(hemb + (size_t)w * Edim);
      float4 hq[4] = {hr[0], hr[1], hr[2], hr[3]};
      const float* he = (const float*)hq;
#pragma unroll
      for (int e = 0; e < Edim; ++e) {
        const float* wr = Ww + (Edim + e) * Hdim + hb;
#pragma unroll
        for (int i = 0; i < 8; ++i) t8[i] = fmaf(he[e], wr[i], t8[i]);
      }
#pragma unroll
      for (int i = 0; i < 8; ++i) {
        float q = dev_tanh(t8[i]);
        float val = (j == 0) ? q : (j == 1) ? (1.f - q * q) : -q;
        o[i] = (_Float16)(Wu[hb + i] * val);
      }
    } else {
#pragma unroll
      for (int i = 0; i < 8; ++i) o[i] = (_Float16)0.f;
    }
    *(f16x8*)(B2 + (size_t)v * 8) = o;
  } else if (idx < PH) {
    int j = idx - PBV;
    int lane = j & 63;
    int e = lane & 15;
    int wb = (j >> 6) * 32 + (lane >> 4) * 8;
    f16x8 v;
#pragma unroll
    for (int i = 0; i < 8; ++i) {
      int w = wb + i;
      v[i] = (w < Wdim) ? (_Float16)hemb[(size_t)w * Edim + e] : (_Float16)0.f;
    }
    *(f16x8*)(hembB + (size_t)j * 8) = v;
  } else if (idx < PZ) {
    numden[idx - PH] = 0.f;
  } else if (idx < PO) {
    outz[idx - PZ] = 0.f;
  }
}

// score_ctx: fused, 32f x 64w per wave, 1024 blocks, XCD-swizzled.
// Stages its own 64f x 128w mask tile into LDS (coalesced, XOR-swizzled),
// issued BEFORE GEMM1. 256-byte ballot probe resolves byte/int32 layout.
// First GEMM SWAPPED: mfma(B_w, A_f) -> D col=f, row=w. Epilogue:
// exp2 * mask(LDS) -> fp16 -> per-wave swizzled sc tile. Second GEMM
// contracts w -> num[32f][16e]; HW fp32 atomics accumulate.
__global__ __launch_bounds__(256) void score_ctx_kernel(
    const _Float16* __restrict__ A2, const _Float16* __restrict__ B2,
    const unsigned char* __restrict__ mask_b, const _Float16* __restrict__ hembB,
    float* __restrict__ num, float* __restrict__ den) {
  __shared__ __align__(16) char smem[16384 + 8192 + 16];
  char* M_base = smem + 16384;          // 8KB mask tile [64f][128w] bytes
  int* s_any = (int*)(smem + 24576);

  const int tid = threadIdx.x;
  const int wid = tid >> 6, lane = tid & 63;
  const int wr = wid >> 1, wc = wid & 1;

  // ---- bijective XCD swizzle (1024 blocks, 8 XCDs)
  const int lin = blockIdx.y * 32 + blockIdx.x;   // grid (32, 32)
  const int nl = (lin & 7) * 128 + (lin >> 3);
  const int bx = nl >> 5;   // w-tile (128 w) index [0,32)
  const int by = nl & 31;   // f-tile (64 f) index [0,32)

  const int fblk = by * 64;
  const int wblk = bx * 128;
  const int fbase = fblk + wr * 32;      // wave owns 32 f
  const int wbase = wblk + wc * 64;      // wave owns 64 w
  const int lrow = lane & 15, g = lane >> 4;

  // ---- mask layout probe (256B; int32 layout has exact zeros at i%4!=0)
  if (tid == 0) *s_any = 0;
  __syncthreads();
  if ((tid & 3) && mask_b[tid]) atomicOr(s_any, 1);
  __syncthreads();
  const int mbyte = *s_any;  // 1 = byte layout, 0 = int32

  // ---- stage mask tile -> LDS (swizzled; issued before GEMM1)
  if (mbyte) {
#pragma unroll
    for (int it = 0; it < 2; ++it) {
      const int t = it * 256 + tid;
      const int row = t >> 3, c16 = t & 7;
      const int f = fblk + row;
      const int w0 = wblk + c16 * 16;
      uint4 mv = make_uint4(0u, 0u, 0u, 0u);
      if (f < Fdim && w0 < Wdim)
        mv = *(const uint4*)(mask_b + (size_t)f * Wdim + w0);
      *(uint4*)(M_base + row * 128 + ((c16 * 16) ^ ((row & 7) << 4))) = mv;
    }
  } else {
    const int* mask_i = (const int*)mask_b;
#pragma unroll
    for (int it = 0; it < 8; ++it) {
      const int t = it * 256 + tid;
      const int row = t >> 5, c4 = t & 31;
      const int f = fblk + row;
      const int w0 = wblk + c4 * 4;
      unsigned int pk = 0u;
      if (f < Fdim && w0 < Wdim) {
        uint4 mi = *(const uint4*)(mask_i + (size_t)f * Wdim + w0);
        pk = (mi.x ? 1u : 0u) | (mi.y ? 1u : 0u) << 8 |
             (mi.z ? 1u : 0u) << 16 | (mi.w ? 1u : 0u) << 24;
      }
      *(unsigned int*)(M_base + row * 128 + ((c4 * 4) ^ ((row & 7) << 4))) = pk;
    }
  }

  // ---- EARLY issue: hembB fragments
  const f16x8 hb0 =
      *(const f16x8*)(hembB + ((size_t)(wbase >> 5) + 0) * 512 + lane * 8);
  const f16x8 hb1 =
      *(const f16x8*)(hembB + ((size_t)(wbase >> 5) + 1) * 512 + lane * 8);

  // ---- first GEMM: accT[mw][nf] = sc^T frags (col=f, row=w)
  f32x4 accT[4][2];
#pragma unroll
  for (int mw = 0; mw < 4; ++mw)
#pragma unroll
    for (int nf = 0; nf < 2; ++nf) accT[mw][nf] = (f32x4){0.f, 0.f, 0.f, 0.f};

  const _Float16* Ab = A2 + ((size_t)(fbase >> 4) * NKS) * 512 + lane * 8;
  const _Float16* Bb = B2 + ((size_t)(wbase >> 4) * NKS) * 512 + lane * 8;
#pragma unroll 2
  for (int ks = 0; ks < NKS; ++ks) {
    f16x8 bw[4], af[2];
#pragma unroll
    for (int mw = 0; mw < 4; ++mw)
      bw[mw] = *(const f16x8*)(Bb + (size_t)(mw * NKS + ks) * 512);
#pragma unroll
    for (int nf = 0; nf < 2; ++nf)
      af[nf] = *(const f16x8*)(Ab + (size_t)(nf * NKS + ks) * 512);
#pragma unroll
    for (int mw = 0; mw < 4; ++mw)
#pragma unroll
      for (int nf = 0; nf < 2; ++nf)
        accT[mw][nf] = __builtin_amdgcn_mfma_f32_16x16x32_f16(
            bw[mw], af[nf], accT[mw][nf], 0, 0, 0);
  }
  __syncthreads();  // mask tile visible to all waves

  // ---- epilogue: exp2 * mask(LDS) -> fp16 -> swizzled sc; den partials
  char* sbase = smem + wid * 4096;
  float denp[2] = {0.f, 0.f};
#pragma unroll
  for (int nf = 0; nf < 2; ++nf) {
    const int flm = wr * 32 + nf * 16 + lrow;   // row in 64-f mask tile
    const int fl = nf * 16 + lrow;              // row in 32-f sc tile
    const int sw = (fl & 7) << 4;
    const int swm = (flm & 7) << 4;
#pragma unroll
    for (int mw = 0; mw < 4; ++mw) {
      const unsigned int u = *(const unsigned int*)(
          M_base + flm * 128 + ((wc * 64 + mw * 16 + g * 4) ^ swm));
      float v[4];
#pragma unroll
      for (int r = 0; r < 4; ++r) {
        const float m = ((u >> (8 * r)) & 0xFFu) ? 1.f : 0.f;
        v[r] = fast_exp2(accT[mw][nf][r] * kLog2e) * m;
        denp[nf] += v[r];
      }
      const int wb0 = (mw * 16 + g * 4) * 2;
      *(f16x2*)(sbase + fl * 128 + ((wb0 + 0) ^ sw)) = pack_f16(v[0], v[1]);
      *(f16x2*)(sbase + fl * 128 + ((wb0 + 4) ^ sw)) = pack_f16(v[2], v[3]);
    }
  }

  // ---- second GEMM: num[32f][16e] over this wave's 64 w
  f32x4 numT[2];
#pragma unroll
  for (int nf = 0; nf < 2; ++nf) numT[nf] = (f32x4){0.f, 0.f, 0.f, 0.f};
#pragma unroll
  for (int kstep = 0; kstep < 2; ++kstep) {
    const f16x8 hb = (kstep == 0) ? hb0 : hb1;
#pragma unroll
    for (int nf = 0; nf < 2; ++nf) {
      const int fl = nf * 16 + lrow;
      const int sw = (fl & 7) << 4;
      const f16x8 scf =
          *(const f16x8*)(sbase + fl * 128 + ((kstep * 64 + g * 16) ^ sw));
      numT[nf] =
          __builtin_amdgcn_mfma_f32_16x16x32_f16(scf, hb, numT[nf], 0, 0, 0);
    }
  }

  // ---- den: sum across the 4 lane-groups (same f, different g)
#pragma unroll
  for (int nf = 0; nf < 2; ++nf) {
    denp[nf] += __shfl_xor(denp[nf], 16, 64);
    denp[nf] += __shfl_xor(denp[nf], 32, 64);
  }

  // ---- accumulate global num/den with HW fp atomics
  if (lane < 16) {
#pragma unroll
    for (int nf = 0; nf < 2; ++nf)
      unsafeAtomicAdd(&den[fbase + nf * 16 + lrow], denp[nf]);
  }
#pragma unroll
  for (int nf = 0; nf < 2; ++nf)
#pragma unroll
    for (int r = 0; r < 4; ++r) {
      const int f = fbase + nf * 16 + g * 4 + r;
      unsafeAtomicAdd(&num[(size_t)f * Edim + lrow], numT[nf][r]);
    }
}

// out[b][e] += sum_{f in chunk} values[b][f] * num[f][e] / den[f]
// grid (Bdim, FSPLIT); out zeroed by prep2; fp32 atomics accumulate.
__global__ __launch_bounds__(256) void out_gemv_kernel(
    const float* __restrict__ values, const float* __restrict__ num,
    const float* __restrict__ den, float* __restrict__ out) {
  const int b = blockIdx.x, tid = threadIdx.x;
  const int f0 = blockIdx.y * FCH;
  float acc[Edim];
#pragma unroll
  for (int e = 0; e < Edim; ++e) acc[e] = 0.f;
  for (int f = f0 + tid; f < f0 + FCH; f += 256) {
    float v = values[b * Fdim + f] * fast_rcp(den[f]);
    const float4* c4 = (const float4*)(num + (size_t)f * Edim);
    float4 c0 = c4[0], c1 = c4[1], c2 = c4[2], c3 = c4[3];
    float cr[Edim] = {c0.x, c0.y, c0.z, c0.w, c1.x, c1.y, c1.z, c1.w,
                      c2.x, c2.y, c2.z, c2.w, c3.x, c3.y, c3.z, c3.w};
#pragma unroll
    for (int e = 0; e < Edim; ++e) acc[e] = fmaf(v, cr[e], acc[e]);
  }
  __shared__ float s_red[4][Edim];
  const int lane = tid & 63, wv = tid >> 6;
#pragma unroll
  for (int e = 0; e < Edim; ++e) {
    float a = wave64_sum(acc[e]);
    if (lane == 63) s_red[wv][e] = a;
  }
  __syncthreads();
  if (tid < Edim) {
    float tot =
        s_red[0][tid] + s_red[1][tid] + s_red[2][tid] + s_red[3][tid];
    unsafeAtomicAdd(&out[b * Edim + tid], tot);
  }
}

extern "C" void kernel_launch(void* const* d_in, const int* in_sizes, int n_in,
                              void* d_out, int out_size, void* d_ws,
                              size_t ws_size, hipStream_t stream) {
  const float* values = (const float*)d_in[0];
  const float* femb   = (const float*)d_in[1];
  const float* hemb   = (const float*)d_in[2];
  const float* Ww     = (const float*)d_in[3];
  const float* bw     = (const float*)d_in[4];
  const float* Wu     = (const float*)d_in[5];
  const unsigned char* mask = (const unsigned char*)d_in[6];
  float* out = (float*)d_out;
  float* ws = (float*)d_ws;

  // ws layout (float units). Total ~2.7 MB.
  const size_t OFF_A = 16;                                // 128*6*512 f16
  const size_t OFF_B = OFF_A + (size_t)128 * NKS * 256;   // 256*6*512 f16
  const size_t OFF_HB = OFF_B + (size_t)256 * NKS * 256;  // 32768 f
  const size_t OFF_PN = OFF_HB + 32768;                   // num Mp*Edim
  const size_t OFF_PD = OFF_PN + (size_t)Mp * Edim;       // den Mp

  _Float16* A2 = (_Float16*)(ws + OFF_A);
  _Float16* B2 = (_Float16*)(ws + OFF_B);
  _Float16* hembB = (_Float16*)(ws + OFF_HB);
  float* num = ws + OFF_PN;
  float* den = ws + OFF_PD;

  constexpr int PTOT = 128 * NKS * 64 + 256 * NKS * 64 + (Np / 32) * 64 +
                       Mp * Edim + Mp + Bdim * Edim;  // 194560 -> 760 blocks
  prep2_kernel<<<dim3(PTOT / 256), dim3(256), 0, stream>>>(
      femb, hemb, Ww, bw, Wu, A2, B2, hembB, num, out);

  score_ctx_kernel<<<dim3(32, 32), dim3(256), 0, stream>>>(
      A2, B2, mask, hembB, num, den);

  out_gemv_kernel<<<dim3(Bdim, FSPLIT), dim3(256), 0, stream>>>(
      values, num, den, out);
}